// Round 1
// baseline (494.993 us; speedup 1.0000x reference)
//
#include <hip/hip_runtime.h>
#include <math.h>

// Problem constants (fixed by the reference).
#define D_TOTAL 21389512LL   // divisible by 4 -> clean float4 vectorization
#define M_MODELS 3
#define PRIOR_SIGMA 0.1

// loss = (M-1)*0.5/sigma^2 * sum(metamean^2)          [W_MM = 100]
//      + 0.5 * sum(log fishers)
//      + C   (analytic constant, computed on host in double)

__global__ __launch_bounds__(256) void bayes_reduce_kernel(
    const float* __restrict__ metamean,   // D floats
    const float* __restrict__ fishers,    // 3*D floats
    float* __restrict__ out,              // 1 float, pre-zeroed
    float constant_term)
{
    const long long nd4 = D_TOTAL / 4;          // metamean float4 count
    const long long nf4 = 3 * D_TOTAL / 4;      // fishers  float4 count
    const long long stride = (long long)gridDim.x * blockDim.x;
    const long long tid0   = (long long)blockIdx.x * blockDim.x + threadIdx.x;

    const float4* mm4 = (const float4*)metamean;
    const float4* ff4 = (const float4*)fishers;

    float acc = 0.0f;

    // Pass 1: (M-1)*0.5/sigma^2 * metamean^2  -> weight 100
    for (long long i = tid0; i < nd4; i += stride) {
        float4 v = mm4[i];
        acc += 100.0f * (v.x * v.x + v.y * v.y + v.z * v.z + v.w * v.w);
    }
    // Pass 2: 0.5 * log(fisher)
    for (long long i = tid0; i < nf4; i += stride) {
        float4 v = ff4[i];
        acc += 0.5f * (__logf(v.x) + __logf(v.y) + __logf(v.z) + __logf(v.w));
    }

    // Wave-64 shuffle reduction
    for (int off = 32; off > 0; off >>= 1)
        acc += __shfl_down(acc, off, 64);

    __shared__ float smem[4];  // 256 threads = 4 waves
    const int lane = threadIdx.x & 63;
    const int wid  = threadIdx.x >> 6;
    if (lane == 0) smem[wid] = acc;
    __syncthreads();

    if (threadIdx.x == 0) {
        float v = smem[0] + smem[1] + smem[2] + smem[3];
        if (blockIdx.x == 0) v += constant_term;  // fold analytic constant exactly once
        atomicAdd(out, v);                        // device-scope, cross-XCD safe
    }
}

extern "C" void kernel_launch(void* const* d_in, const int* in_sizes, int n_in,
                              void* d_out, int out_size, void* d_ws, size_t ws_size,
                              hipStream_t stream) {
    const float* metamean = (const float*)d_in[0];
    // d_in[1] = means: mathematically unused (Mahalanobis term is identically 0) -> never read.
    const float* fishers  = (const float*)d_in[2];
    float* out = (float*)d_out;

    // Analytic constant in double precision:
    //   C = (M-1)*D*(log sigma + 0.5*log 2pi) - 0.5*M*D*log 2pi
    const double log2pi = 1.8378770664093453;
    const double logsig = -2.302585092994045684;  // log(0.1)
    const double C = (double)(M_MODELS - 1) * (double)D_TOTAL * (logsig + 0.5 * log2pi)
                   - 0.5 * (double)M_MODELS * (double)D_TOTAL * log2pi;

    hipMemsetAsync(out, 0, sizeof(float), stream);

    // 4096 blocks x 256 threads = 1M threads over 21.4M float4 -> ~20 vec-iters/thread
    const int blocks = 4096;
    bayes_reduce_kernel<<<blocks, 256, 0, stream>>>(metamean, fishers, out, (float)C);
}

// Round 2
// 494.988 us; speedup vs baseline: 1.0000x; 1.0000x over previous
//
#include <hip/hip_runtime.h>
#include <math.h>

// Problem constants (fixed by the reference).
#define D_TOTAL 21389512LL   // divisible by 4 -> clean float4 vectorization
#define M_MODELS 3

// loss = (M-1)*0.5/sigma^2 * sum(metamean^2)   [weight = 100]
//      + 0.5 * sum(log fishers)
//      + C   (analytic constant, double-precision on host)
//
// `means` (input 1) is mathematically unused: the Mahalanobis term
// sum(fisher * (means - means)^2) is identically zero. Never read -> traffic
// floor is metamean (85.6 MB) + fishers (256.7 MB) = 342 MB.

#define NBLOCKS 4096

__global__ __launch_bounds__(256) void bayes_partial_kernel(
    const float* __restrict__ metamean,   // D floats
    const float* __restrict__ fishers,    // 3*D floats
    float* __restrict__ partial)          // NBLOCKS floats (pure store, no init needed)
{
    const long long nd4 = D_TOTAL / 4;
    const long long nf4 = 3 * D_TOTAL / 4;
    const long long stride = (long long)gridDim.x * blockDim.x;
    const long long tid0   = (long long)blockIdx.x * blockDim.x + threadIdx.x;

    const float4* mm4 = (const float4*)metamean;
    const float4* ff4 = (const float4*)fishers;

    float acc = 0.0f;

    // ---- Pass 1: 100 * metamean^2, unrolled x4 for 4 loads in flight ----
    {
        long long i = tid0;
        for (; i + 3 * stride < nd4; i += 4 * stride) {
            float4 a = mm4[i];
            float4 b = mm4[i + stride];
            float4 c = mm4[i + 2 * stride];
            float4 d = mm4[i + 3 * stride];
            float s0 = a.x*a.x + a.y*a.y + a.z*a.z + a.w*a.w;
            float s1 = b.x*b.x + b.y*b.y + b.z*b.z + b.w*b.w;
            float s2 = c.x*c.x + c.y*c.y + c.z*c.z + c.w*c.w;
            float s3 = d.x*d.x + d.y*d.y + d.z*d.z + d.w*d.w;
            acc += 100.0f * ((s0 + s1) + (s2 + s3));
        }
        for (; i < nd4; i += stride) {
            float4 a = mm4[i];
            acc += 100.0f * (a.x*a.x + a.y*a.y + a.z*a.z + a.w*a.w);
        }
    }

    // ---- Pass 2: 0.5 * log(fisher), unrolled x4 ----
    {
        long long i = tid0;
        for (; i + 3 * stride < nf4; i += 4 * stride) {
            float4 a = ff4[i];
            float4 b = ff4[i + stride];
            float4 c = ff4[i + 2 * stride];
            float4 d = ff4[i + 3 * stride];
            float s0 = __logf(a.x) + __logf(a.y) + __logf(a.z) + __logf(a.w);
            float s1 = __logf(b.x) + __logf(b.y) + __logf(b.z) + __logf(b.w);
            float s2 = __logf(c.x) + __logf(c.y) + __logf(c.z) + __logf(c.w);
            float s3 = __logf(d.x) + __logf(d.y) + __logf(d.z) + __logf(d.w);
            acc += 0.5f * ((s0 + s1) + (s2 + s3));
        }
        for (; i < nf4; i += stride) {
            float4 a = ff4[i];
            acc += 0.5f * (__logf(a.x) + __logf(a.y) + __logf(a.z) + __logf(a.w));
        }
    }

    // ---- Wave-64 shuffle reduction, then block reduce ----
    for (int off = 32; off > 0; off >>= 1)
        acc += __shfl_down(acc, off, 64);

    __shared__ float smem[4];
    const int lane = threadIdx.x & 63;
    const int wid  = threadIdx.x >> 6;
    if (lane == 0) smem[wid] = acc;
    __syncthreads();

    if (threadIdx.x == 0)
        partial[blockIdx.x] = (smem[0] + smem[1]) + (smem[2] + smem[3]);
}

__global__ __launch_bounds__(256) void bayes_final_kernel(
    const float* __restrict__ partial, float* __restrict__ out, float constant_term)
{
    // NBLOCKS = 4096 partials, 256 threads -> 16 each via float4 x4
    const float4* p4 = (const float4*)partial;
    float acc = 0.0f;
    for (int i = threadIdx.x; i < NBLOCKS / 4; i += 256) {
        float4 v = p4[i];
        acc += (v.x + v.y) + (v.z + v.w);
    }
    for (int off = 32; off > 0; off >>= 1)
        acc += __shfl_down(acc, off, 64);

    __shared__ float smem[4];
    const int lane = threadIdx.x & 63;
    const int wid  = threadIdx.x >> 6;
    if (lane == 0) smem[wid] = acc;
    __syncthreads();

    if (threadIdx.x == 0)
        out[0] = (smem[0] + smem[1]) + (smem[2] + smem[3]) + constant_term;
}

extern "C" void kernel_launch(void* const* d_in, const int* in_sizes, int n_in,
                              void* d_out, int out_size, void* d_ws, size_t ws_size,
                              hipStream_t stream) {
    const float* metamean = (const float*)d_in[0];
    // d_in[1] = means: unused (Mahalanobis term identically 0) -> never read.
    const float* fishers  = (const float*)d_in[2];
    float* out     = (float*)d_out;
    float* partial = (float*)d_ws;   // NBLOCKS floats of scratch, pure-store

    // C = (M-1)*D*(log sigma + 0.5*log 2pi) - 0.5*M*D*log 2pi, in double.
    const double log2pi = 1.8378770664093453;
    const double logsig = -2.302585092994045684;  // log(0.1)
    const double C = (double)(M_MODELS - 1) * (double)D_TOTAL * (logsig + 0.5 * log2pi)
                   - 0.5 * (double)M_MODELS * (double)D_TOTAL * log2pi;

    bayes_partial_kernel<<<NBLOCKS, 256, 0, stream>>>(metamean, fishers, partial);
    bayes_final_kernel<<<1, 256, 0, stream>>>(partial, out, (float)C);
}